// Round 5
// baseline (37.715 us; speedup 1.0000x reference)
//
#include <hip/hip_runtime.h>
#include <hip/hip_bf16.h>

constexpr int B = 1024, S = 128, E = 256, C = 256, T = 12;

typedef short s8v __attribute__((ext_vector_type(8)));   // 8 x bf16 bits
typedef float f4v __attribute__((ext_vector_type(4)));

__device__ __forceinline__ short f2bf(float f) {
    unsigned u = __builtin_bit_cast(unsigned, f);
    return (short)((u + 0x7FFFu + ((u >> 16) & 1u)) >> 16);
}
__device__ __forceinline__ s8v cvt8(float4 a, float4 b) {
    s8v o;
    o[0] = f2bf(a.x); o[1] = f2bf(a.y); o[2] = f2bf(a.z); o[3] = f2bf(a.w);
    o[4] = f2bf(b.x); o[5] = f2bf(b.y); o[6] = f2bf(b.z); o[7] = f2bf(b.w);
    return o;
}

// ---------------- Kernel 1: pred[t] = c_last @ Wk_w[t]^T (bias cancels in log-softmax) ----
// 128x128 tiles, 512 threads, reads c/wkw f32 directly (cvt in staging). Also zeroes out[0].
__global__ __launch_bounds__(512) void pred_kernel(
    const float* __restrict__ c, const float* __restrict__ wkw,
    const int* __restrict__ tsp, short* __restrict__ pred, float* __restrict__ out)
{
    // bijective XCD swizzle: 192 blocks = 8 xcd * 24; (t,eb) pairs clustered per xcd
    int wgid = blockIdx.x;
    int xcd = wgid & 7, q = wgid >> 3;          // q in 0..23
    int pr = xcd * 3 + (q >> 3);                // 0..23 : (t,eb) pair id
    int bb = q & 7;                              // b-row block (128 rows)
    int t = pr >> 1, eb = pr & 1;                // e-col block (128 cols)
    if (wgid == 0 && threadIdx.x == 0) out[0] = 0.0f;
    const int ts = tsp[0];

    __shared__ __align__(16) short AS[128 * 256];   // c_last tile (bf16), 64 KB
    __shared__ __align__(16) short BS[128 * 256];   // wkw tile (bf16), 64 KB
    const int tid = threadIdx.x;

    #pragma unroll
    for (int it = 0; it < 8; ++it) {
        int idx = it * 512 + tid;
        int r = idx >> 5, s = idx & 31;
        const float4* pa = reinterpret_cast<const float4*>(
            c + (size_t)(bb * 128 + r) * S * C + (size_t)ts * C + s * 8);
        *reinterpret_cast<s8v*>(AS + r * 256 + ((s ^ (r & 7)) * 8)) = cvt8(pa[0], pa[1]);
        const float4* pb = reinterpret_cast<const float4*>(
            wkw + ((size_t)t * E + eb * 128 + r) * 256 + s * 8);
        *reinterpret_cast<s8v*>(BS + r * 256 + ((s ^ (r & 7)) * 8)) = cvt8(pb[0], pb[1]);
    }
    __syncthreads();

    const int wv = tid >> 6, ln = tid & 63;
    const int wr = wv >> 2, wc = wv & 3;        // 2 row-groups(64) x 4 col-groups(32)
    const int lr = ln & 15, lg = ln >> 4;
    f4v acc[4][2] = {};

    #pragma unroll
    for (int kk = 0; kk < 8; ++kk) {
        int slot = kk * 4 + lg;
        s8v a[4], b[2];
        #pragma unroll
        for (int m = 0; m < 4; ++m) {
            int r = wr * 64 + m * 16 + lr;
            a[m] = *reinterpret_cast<const s8v*>(AS + r * 256 + ((slot ^ (r & 7)) * 8));
        }
        #pragma unroll
        for (int n = 0; n < 2; ++n) {
            int r = wc * 32 + n * 16 + lr;
            b[n] = *reinterpret_cast<const s8v*>(BS + r * 256 + ((slot ^ (r & 7)) * 8));
        }
        #pragma unroll
        for (int m = 0; m < 4; ++m)
            #pragma unroll
            for (int n = 0; n < 2; ++n)
                acc[m][n] = __builtin_amdgcn_mfma_f32_16x16x32_bf16(a[m], b[n], acc[m][n], 0, 0, 0);
    }

    #pragma unroll
    for (int m = 0; m < 4; ++m)
        #pragma unroll
        for (int n = 0; n < 2; ++n)
            #pragma unroll
            for (int i = 0; i < 4; ++i) {
                int bg = bb * 128 + wr * 64 + m * 16 + lg * 4 + i;   // b row
                int eg = eb * 128 + wc * 32 + n * 16 + lr;           // e col
                pred[(size_t)t * B * E + (size_t)bg * E + eg] = f2bf(acc[m][n][i]);
            }
}

// ---------------- Kernel 2: full-row scores + online logsumexp + diag + atomic reduce ----
// block = (rb: 64 enc rows, t). 512 thr, 8 waves (2 row x 4 col groups). Loops 4 col-chunks
// of 256, each in 8 K-eighths (dbuf LDS + 2-deep reg prefetch, 1 barrier/eighth).
// Online (m,s) per row per wave across chunks; merge across waves at end; atomicAdd out.
__global__ __launch_bounds__(512) void score_kernel(
    const float* __restrict__ z, const short* __restrict__ pred,
    const int* __restrict__ tsp, float* __restrict__ out)
{
    const int wgid = blockIdx.x;
    const int t = wgid >> 4, rb = wgid & 15;
    const int ts = tsp[0];

    __shared__ __align__(16) char SM[65536];
    short* encS = reinterpret_cast<short*>(SM);              // 64x256 bf16 = 32 KB
    short* buf0 = reinterpret_cast<short*>(SM + 32768);      // pred eighth [4][256][8] = 16 KB
    short* buf1 = reinterpret_cast<short*>(SM + 49152);      // 16 KB
    float* pm    = reinterpret_cast<float*>(SM + 32768);     // aliased after final barrier
    float* ps    = pm + 256;                                  // [4 wc][64 rows]
    float* diagS = ps + 256;                                  // [64]

    const int tid = threadIdx.x;
    const short* pred_t = pred + (size_t)t * B * E;

    // per-thread pred staging addresses: 2 x 16B per eighth (1024 (col,slot) pairs)
    const int col0 = tid >> 2,          sl0 = tid & 3;
    const int col1 = (tid + 512) >> 2,  sl1 = tid & 3;
    const short* base0 = pred_t + (size_t)col0 * 256 + sl0 * 8;
    const short* base1 = pred_t + (size_t)col1 * 256 + sl1 * 8;
    const int l0 = sl0 * 2048 + col0 * 8;
    const int l1 = sl1 * 2048 + col1 * 8;

    // prologue: issue eighth-0, stage enc from z (f32->bf16), write eighth-0, issue eighth-1
    s8v R0 = *reinterpret_cast<const s8v*>(base0);
    s8v R1 = *reinterpret_cast<const s8v*>(base1);
    #pragma unroll
    for (int it = 0; it < 4; ++it) {
        int idx = it * 512 + tid;
        int r = idx >> 5, s = idx & 31;
        const float4* pz = reinterpret_cast<const float4*>(
            z + (size_t)(rb * 64 + r) * S * E + (size_t)(ts + 1 + t) * E + s * 8);
        *reinterpret_cast<s8v*>(encS + r * 256 + ((s ^ (r & 7)) * 8)) = cvt8(pz[0], pz[1]);
    }
    *reinterpret_cast<s8v*>(buf0 + l0) = R0;
    *reinterpret_cast<s8v*>(buf0 + l1) = R1;
    R0 = *reinterpret_cast<const s8v*>(base0 + 32);
    R1 = *reinterpret_cast<const s8v*>(base1 + 32);
    __syncthreads();

    const int wv = tid >> 6, ln = tid & 63;
    const int wr = wv >> 2, wc = wv & 3;          // 2 row-groups(32) x 4 col-groups(64)
    const int lr = ln & 15, lg = ln >> 4;
    f4v acc[4][2] = {};
    float m_run[2] = {-1e30f, -1e30f};
    float s_run[2] = {0.0f, 0.0f};
    float dreg[2] = {0.0f, 0.0f};
    int downer[2] = {0, 0};

    #pragma unroll
    for (int ci = 0; ci < 4; ++ci) {
        #pragma unroll
        for (int ke = 0; ke < 8; ++ke) {
            const int Eix = ci * 8 + ke;
            short* cur = (Eix & 1) ? buf1 : buf0;
            short* nxt = (Eix & 1) ? buf0 : buf1;
            if (Eix < 31) {   // write prefetched eighth Eix+1
                *reinterpret_cast<s8v*>(nxt + l0) = R0;
                *reinterpret_cast<s8v*>(nxt + l1) = R1;
            }
            if (Eix < 30) {   // issue loads for eighth Eix+2
                const int E2 = Eix + 2;
                const int off = (E2 >> 3) * 65536 + (E2 & 7) * 32;
                R0 = *reinterpret_cast<const s8v*>(base0 + off);
                R1 = *reinterpret_cast<const s8v*>(base1 + off);
            }
            // MFMA on eighth Eix
            s8v p[4], e[2];
            #pragma unroll
            for (int a = 0; a < 4; ++a)
                p[a] = *reinterpret_cast<const s8v*>(cur + lg * 2048 + (wc * 64 + a * 16 + lr) * 8);
            #pragma unroll
            for (int b = 0; b < 2; ++b) {
                int er = wr * 32 + b * 16 + lr;
                int sf = ke * 4 + lg;
                e[b] = *reinterpret_cast<const s8v*>(encS + er * 256 + ((sf ^ (er & 7)) * 8));
            }
            #pragma unroll
            for (int a = 0; a < 4; ++a)
                #pragma unroll
                for (int b = 0; b < 2; ++b)
                    acc[a][b] = __builtin_amdgcn_mfma_f32_16x16x32_bf16(p[a], e[b], acc[a][b], 0, 0, 0);

            if (ke == 7) {   // chunk complete: online update + diag capture, reset acc
                #pragma unroll
                for (int b = 0; b < 2; ++b) {
                    float mx = -1e30f;
                    #pragma unroll
                    for (int a = 0; a < 4; ++a)
                        #pragma unroll
                        for (int i = 0; i < 4; ++i) mx = fmaxf(mx, acc[a][b][i]);
                    mx = fmaxf(mx, __shfl_xor(mx, 16));
                    mx = fmaxf(mx, __shfl_xor(mx, 32));
                    float sm = 0.0f;
                    #pragma unroll
                    for (int a = 0; a < 4; ++a)
                        #pragma unroll
                        for (int i = 0; i < 4; ++i) sm += __expf(acc[a][b][i] - mx);
                    sm += __shfl_xor(sm, 16);
                    sm += __shfl_xor(sm, 32);

                    int rg = rb * 64 + wr * 32 + b * 16 + lr;
                    if ((rg >> 8) == ci) {
                        int dl = rg & 255;
                        if ((dl >> 6) == wc && ((dl >> 2) & 3) == lg) {
                            #pragma unroll
                            for (int a = 0; a < 4; ++a)
                                #pragma unroll
                                for (int i = 0; i < 4; ++i)
                                    if (((dl >> 4) & 3) == a && (dl & 3) == i) dreg[b] = acc[a][b][i];
                            downer[b] = 1;
                        }
                    }
                    float mn = fmaxf(m_run[b], mx);
                    s_run[b] = s_run[b] * __expf(m_run[b] - mn) + sm * __expf(mx - mn);
                    m_run[b] = mn;
                    #pragma unroll
                    for (int a = 0; a < 4; ++a)
                        #pragma unroll
                        for (int i = 0; i < 4; ++i) acc[a][b][i] = 0.0f;
                }
            }
            __syncthreads();
        }
    }

    // epilogue: publish per-wave stats + diag (aliasing buf0 region - safe after last barrier)
    if (lg == 0) {
        pm[wc * 64 + wr * 32 + lr]      = m_run[0];
        ps[wc * 64 + wr * 32 + lr]      = s_run[0];
        pm[wc * 64 + wr * 32 + 16 + lr] = m_run[1];
        ps[wc * 64 + wr * 32 + 16 + lr] = s_run[1];
    }
    if (downer[0]) diagS[wr * 32 + lr]      = dreg[0];
    if (downer[1]) diagS[wr * 32 + 16 + lr] = dreg[1];
    __syncthreads();

    if (tid < 64) {
        float M = pm[tid];
        #pragma unroll
        for (int w = 1; w < 4; ++w) M = fmaxf(M, pm[w * 64 + tid]);
        float Ss = 0.0f;
        #pragma unroll
        for (int w = 0; w < 4; ++w) Ss += ps[w * 64 + tid] * __expf(pm[w * 64 + tid] - M);
        float val = diagS[tid] - (M + logf(Ss));
        #pragma unroll
        for (int o = 1; o < 64; o <<= 1) val += __shfl_xor(val, o);
        if (tid == 0) atomicAdd(out, -val / (float)(B * T));
    }
}

extern "C" void kernel_launch(void* const* d_in, const int* in_sizes, int n_in,
                              void* d_out, int out_size, void* d_ws, size_t ws_size,
                              hipStream_t stream)
{
    (void)in_sizes; (void)n_in; (void)out_size; (void)ws_size;
    const float* z   = (const float*)d_in[0];
    const float* c   = (const float*)d_in[1];
    const float* wkw = (const float*)d_in[2];
    const int*   tsp = (const int*)d_in[4];

    short* pred = (short*)d_ws;                  // T*B*E bf16 = 6,291,456 B

    pred_kernel<<<192, 512, 0, stream>>>(c, wkw, tsp, pred, (float*)d_out);
    score_kernel<<<192, 512, 0, stream>>>(z, pred, tsp, (float*)d_out);
}